// Round 9
// baseline (190.601 us; speedup 1.0000x reference)
//
#include <hip/hip_runtime.h>
#include <math.h>

#define B_  2
#define S_  2048
#define D_  1024
#define H_  16
#define HD_ 64
#define M_  (B_*S_)

typedef unsigned short ushort_t;
typedef unsigned int   uint_t;
typedef __attribute__((ext_vector_type(8))) short bf16x8;
typedef __attribute__((ext_vector_type(4))) float f32x4;

__device__ __forceinline__ ushort_t f2bf(float f) {
    uint_t u = __builtin_bit_cast(uint_t, f);
    u += 0x7FFFu + ((u >> 16) & 1u);           // RNE
    return (ushort_t)(u >> 16);
}
__device__ __forceinline__ float bf2f(ushort_t h) {
    uint_t u = (uint_t)h << 16;
    return __builtin_bit_cast(float, u);
}
// truncating pack: two f32 -> (bf16(lo) | bf16(hi)<<16), one v_perm_b32
__device__ __forceinline__ uint_t pkt(float lo, float hi) {
    return __builtin_amdgcn_perm(__builtin_bit_cast(uint_t, hi),
                                 __builtin_bit_cast(uint_t, lo), 0x07060302u);
}
// async global->LDS, 16B per lane; lds addr = wave-uniform base + lane*16
__device__ __forceinline__ void dma16(const ushort_t* g, ushort_t* l) {
    __builtin_amdgcn_global_load_lds(
        (const __attribute__((address_space(1))) uint_t*)g,
        (__attribute__((address_space(3))) uint_t*)l, 16, 0, 0);
}
// swizzled fragment read from unpadded [row][64] bf16 tile
__device__ __forceinline__ bf16x8 fragr(const ushort_t* base, int row, int chunk) {
    return *(const bf16x8*)&base[row * 64 + (((chunk ^ (row & 7)) << 3))];
}

// ---------------------------------------------------------------------------
// prep: (a) 3 weight transposes f32->bf16  (b) q f32->bf16  (c) K->Kb bf16,
// V->VT bf16 * gamma^{-ml}, per-chunk G^T (bf16) for the state recurrence.
// Flattened grid: [0,3072) transp | [3072,7168) q cvt | [7168,8192) kv+G.
// ---------------------------------------------------------------------------
__global__ __launch_bounds__(256)
void prep(const float* __restrict__ W0, const float* __restrict__ W1,
          const float* __restrict__ W2, ushort_t* __restrict__ T0,
          ushort_t* __restrict__ T1, ushort_t* __restrict__ T2,
          const float* __restrict__ q, ushort_t* __restrict__ q_bf,
          const float* __restrict__ K, const float* __restrict__ V,
          const float* __restrict__ gammas, ushort_t* __restrict__ Kb,
          ushort_t* __restrict__ VT, ushort_t* __restrict__ Gg) {
    __shared__ ushort_t sh[9216];   // 18 KB, reused per branch
    const int bi = blockIdx.x;
    const int tid = threadIdx.x;

    if (bi < 3072) {                // ---- weight transpose+convert
        float* T = (float*)sh;      // [32][36]
        const int z = bi >> 10, rem = bi & 1023;
        const int kt = rem & 31, nt = rem >> 5;
        const float*  W  = (z == 0) ? W0 : (z == 1) ? W1 : W2;
        ushort_t*     WT = (z == 0) ? T0 : (z == 1) ? T1 : T2;
        const int rr = tid >> 3, cc = (tid & 7) * 4;
        float4 w4 = *(const float4*)(W + (size_t)(kt * 32 + rr) * D_ + nt * 32 + cc);
        T[rr * 36 + cc + 0] = w4.x; T[rr * 36 + cc + 1] = w4.y;
        T[rr * 36 + cc + 2] = w4.z; T[rr * 36 + cc + 3] = w4.w;
        __syncthreads();
        ushort_t o[4];
        #pragma unroll
        for (int j = 0; j < 4; ++j) o[j] = f2bf(T[(cc + j) * 36 + rr]);
        *(ushort4*)(WT + (size_t)(nt * 32 + rr) * D_ + kt * 32 + cc) =
            make_ushort4(o[0], o[1], o[2], o[3]);
        return;
    }
    if (bi < 7168) {                // ---- q convert
        const int i = ((bi - 3072) * 256 + tid) * 4;
        float4 x = *(const float4*)(q + i);
        *(ushort4*)(q_bf + i) = make_ushort4(f2bf(x.x), f2bf(x.y), f2bf(x.z), f2bf(x.w));
        return;
    }
    // ---- K/V convert + chunk outer product G^T
    ushort_t* Tv = sh;              // [val][ml] stride 72 (first 64*72=4608)
    ushort_t* Tk = sh + 4608;       // [kappa][ml] stride 72
    const int rem = bi - 7168;
    const int mt = rem & 31, h = (rem >> 5) & 15, b = rem >> 9;
    const int m0 = mt * 64;
    const int r = tid >> 2, c0 = (tid & 3) * 16;
    const float lg = log2f(gammas[h]);
    const float gm = exp2f(-(float)r * lg);
    {
        const float* src = K + ((size_t)(b * S_ + m0 + r)) * D_ + h * HD_ + c0;
        ushort_t kb[16];
        #pragma unroll
        for (int j4 = 0; j4 < 4; ++j4) {
            float4 x = *(const float4*)(src + j4 * 4);
            kb[j4 * 4 + 0] = f2bf(x.x); kb[j4 * 4 + 1] = f2bf(x.y);
            kb[j4 * 4 + 2] = f2bf(x.z); kb[j4 * 4 + 3] = f2bf(x.w);
        }
        ushort_t* dst = Kb + ((size_t)(b * S_ + m0 + r)) * D_ + h * HD_ + c0;
        *(uint4*)(dst + 0) = *(const uint4*)&kb[0];
        *(uint4*)(dst + 8) = *(const uint4*)&kb[8];
        #pragma unroll
        for (int j = 0; j < 16; ++j) Tk[(c0 + j) * 72 + r] = kb[j];
    }
    {
        const float* src = V + ((size_t)(b * S_ + m0 + r)) * D_ + h * HD_ + c0;
        #pragma unroll
        for (int j4 = 0; j4 < 4; ++j4) {
            float4 x = *(const float4*)(src + j4 * 4);
            Tv[(c0 + j4 * 4 + 0) * 72 + r] = f2bf(x.x * gm);
            Tv[(c0 + j4 * 4 + 1) * 72 + r] = f2bf(x.y * gm);
            Tv[(c0 + j4 * 4 + 2) * 72 + r] = f2bf(x.z * gm);
            Tv[(c0 + j4 * 4 + 3) * 72 + r] = f2bf(x.w * gm);
        }
    }
    __syncthreads();
    {
        ushort_t* dst = VT + ((size_t)((b * H_ + h) * HD_ + r)) * S_ + m0 + c0;
        *(uint4*)(dst + 0) = *(const uint4*)&Tv[r * 72 + c0 + 0];
        *(uint4*)(dst + 8) = *(const uint4*)&Tv[r * 72 + c0 + 8];
    }
    const int w = tid >> 6, lane = tid & 63, quad = lane >> 4, l15 = lane & 15;
    bf16x8 af0 = *(const bf16x8*)&Tv[(w * 16 + l15) * 72 + quad * 8];
    bf16x8 af1 = *(const bf16x8*)&Tv[(w * 16 + l15) * 72 + 32 + quad * 8];
    ushort_t* gout = Gg + ((size_t)((b * H_ + h) * 32 + mt)) * 4096;
    #pragma unroll
    for (int kt2 = 0; kt2 < 4; ++kt2) {
        bf16x8 bf0 = *(const bf16x8*)&Tk[(kt2 * 16 + l15) * 72 + quad * 8];
        bf16x8 bf1 = *(const bf16x8*)&Tk[(kt2 * 16 + l15) * 72 + 32 + quad * 8];
        f32x4 g = {};
        g = __builtin_amdgcn_mfma_f32_16x16x32_bf16(af0, bf0, g, 0, 0, 0);
        g = __builtin_amdgcn_mfma_f32_16x16x32_bf16(af1, bf1, g, 0, 0, 0);
        #pragma unroll
        for (int reg = 0; reg < 4; ++reg)
            gout[(w * 16 + quad * 4 + reg) * 64 + kt2 * 16 + l15] = f2bf(g[reg]);
    }
}

// ---------------------------------------------------------------------------
// State scan: S_c = gamma^64 * (S_{c-1} + G_{c-1}); store S_c bf16.
// ---------------------------------------------------------------------------
__global__ __launch_bounds__(256)
void state_scan(const ushort_t* __restrict__ Gg, const float* __restrict__ gammas,
                ushort_t* __restrict__ Sb) {
    const int sl = blockIdx.x, h = blockIdx.y, b = blockIdx.z;
    const float g64 = exp2f(64.0f * log2f(gammas[h]));
    const int r = threadIdx.x >> 4;
    const int cb = (threadIdx.x & 15) * 4;
    const size_t base = ((size_t)((b * H_ + h) * 32)) * 4096 + (sl * 16 + r) * 64 + cb;
    float4 S = make_float4(0.f, 0.f, 0.f, 0.f);
    for (int c = 0; c < 32; ++c) {
        ushort4 g4 = *(const ushort4*)(Gg + base + (size_t)c * 4096);
        ushort4 sb;
        sb.x = f2bf(S.x); sb.y = f2bf(S.y); sb.z = f2bf(S.z); sb.w = f2bf(S.w);
        *(ushort4*)(Sb + base + (size_t)c * 4096) = sb;
        S.x = g64 * (S.x + bf2f(g4.x)); S.y = g64 * (S.y + bf2f(g4.y));
        S.z = g64 * (S.z + bf2f(g4.z)); S.w = g64 * (S.w + bf2f(g4.w));
    }
}

// ---------------------------------------------------------------------------
// Fused dual GEMM + chunk-scan epilogue, double-buffered DMA staging.
// PH[m*D+d] = pack(Pp bf16 | Hloc bf16).
// ---------------------------------------------------------------------------
__global__ __launch_bounds__(256)
void gemm_dual_scan(const ushort_t* __restrict__ A, const ushort_t* __restrict__ BTi,
                    const ushort_t* __restrict__ BTg, const float* __restrict__ bi,
                    const float* __restrict__ bg, uint_t* __restrict__ PH,
                    float* __restrict__ cA, float* __restrict__ cU) {
    __shared__ ushort_t smem[32768];   // 64 KB = 2 x (As 8192 | Bi 4096 | Bg 4096)
    const int tid = threadIdx.x;
    const int n0 = blockIdx.x * 64, m0 = blockIdx.y * 128;
    const int w = tid >> 6, lane = tid & 63, quad = lane >> 4, l15 = lane & 15;
    const int wr = (w >> 1) * 64, wc = (w & 1) * 32;
    const int l8 = lane & 7, lr8 = lane >> 3;

    f32x4 acc_i[4][2] = {};
    f32x4 acc_g[4][2] = {};

    auto stage = [&](int k0, int bufo) {
        #pragma unroll
        for (int t = 0; t < 4; ++t) {
            const int row = w * 32 + t * 8 + lr8;
            const int gc = ((l8 ^ (row & 7)) << 3);
            dma16(A + (size_t)(m0 + row) * D_ + k0 + gc, &smem[bufo + row * 64 + l8 * 8]);
        }
        #pragma unroll
        for (int t = 0; t < 2; ++t) {
            const int row = w * 16 + t * 8 + lr8;
            const int gc = ((l8 ^ (row & 7)) << 3);
            dma16(BTi + (size_t)(n0 + row) * D_ + k0 + gc, &smem[bufo + 8192 + row * 64 + l8 * 8]);
            dma16(BTg + (size_t)(n0 + row) * D_ + k0 + gc, &smem[bufo + 12288 + row * 64 + l8 * 8]);
        }
    };

    stage(0, 0);
    __syncthreads();
    for (int t = 0; t < 16; ++t) {
        const int bufo = (t & 1) * 16384;
        if (t < 15) stage((t + 1) * 64, 16384 - bufo);
        const ushort_t* As = smem + bufo;
        const ushort_t* Bi = smem + bufo + 8192;
        const ushort_t* Bg = smem + bufo + 12288;
        #pragma unroll
        for (int kk = 0; kk < 2; ++kk) {
            bf16x8 af[4], bfi[2], bfg[2];
            #pragma unroll
            for (int i = 0; i < 4; ++i)
                af[i] = fragr(As, wr + 16 * i + l15, kk * 4 + quad);
            #pragma unroll
            for (int j = 0; j < 2; ++j) {
                bfi[j] = fragr(Bi, wc + 16 * j + l15, kk * 4 + quad);
                bfg[j] = fragr(Bg, wc + 16 * j + l15, kk * 4 + quad);
            }
            #pragma unroll
            for (int i = 0; i < 4; ++i)
                #pragma unroll
                for (int j = 0; j < 2; ++j) {
                    acc_i[i][j] = __builtin_amdgcn_mfma_f32_16x16x32_bf16(
                        af[i], bfi[j], acc_i[i][j], 0, 0, 0);
                    acc_g[i][j] = __builtin_amdgcn_mfma_f32_16x16x32_bf16(
                        af[i], bfg[j], acc_g[i][j], 0, 0, 0);
                }
        }
        __syncthreads();
    }

    // epilogue in dead staging LDS: Us bf16 [128][64], Gu u16 [128][64]
    ushort_t* Us = smem;
    ushort_t* Gu = smem + 8192;
    #pragma unroll
    for (int j = 0; j < 2; ++j) {
        const int n = wc + 16 * j + l15;
        const float bbi = bi[n0 + n], bbg = bg[n0 + n];
        #pragma unroll
        for (int i = 0; i < 4; ++i) {
            #pragma unroll
            for (int r = 0; r < 4; ++r) {
                const int m = wr + 16 * i + quad * 4 + r;
                Us[m * 64 + n] = f2bf(acc_i[i][j][r] + bbi);
                float g = 1.0f / (1.0f + __expf(-(acc_g[i][j][r] + bbg)));
                Gu[m * 64 + n] = (ushort_t)__float2uint_rn(g * 65535.0f);
            }
        }
    }
    __syncthreads();

    const int nl = tid & 63, c = tid >> 6;
    const int gmb = m0 + c * 32;
    const size_t gbase = (size_t)gmb * D_ + n0 + nl;
    float Aa = 1.0f, hh = 0.0f;
    #pragma unroll 4
    for (int j = 0; j < 32; ++j) {
        const float g = (float)Gu[(c * 32 + j) * 64 + nl] * (1.0f / 65535.0f);
        const float u = bf2f(Us[(c * 32 + j) * 64 + nl]);
        Aa *= g;
        hh = fmaf(g, hh, u);
        PH[gbase + (size_t)j * D_] = pkt(Aa, hh);
    }
    const int bb = gmb >> 11;
    const int ch = (gmb & 2047) >> 5;
    const int ci = ((bb * 64 + ch) << 10) + n0 + nl;
    cA[ci] = Aa;
    cU[ci] = hh;
}

__global__ __launch_bounds__(64)
void scan_pass2(const float* __restrict__ cA, const float* __restrict__ cU,
                float* __restrict__ cIn) {
    const int t = blockIdx.x * 64 + threadIdx.x;
    const int d = t & 1023, b = t >> 10;
    float h = 0.0f;
    for (int c0 = 0; c0 < 64; c0 += 16) {
        float Av[16], Uv[16];
        #pragma unroll
        for (int j = 0; j < 16; ++j) {
            const int idx = ((b * 64 + c0 + j) << 10) + d;
            Av[j] = cA[idx]; Uv[j] = cU[idx];
        }
        #pragma unroll
        for (int j = 0; j < 16; ++j) {
            cIn[((b * 64 + c0 + j) << 10) + d] = h;
            h = fmaf(Av[j], h, Uv[j]);
        }
    }
}

// h = Hloc + cIn[chunk] * Pp  -> bf16
__global__ __launch_bounds__(256)
void scan_fix(const uint_t* __restrict__ PH, const float* __restrict__ cIn,
              ushort_t* __restrict__ hout) {
    const int i = (blockIdx.x * 256 + threadIdx.x) * 4;
    const int m = i >> 10, d = i & 1023;
    const int b = m >> 11, ch = (m & 2047) >> 5;
    uint4 p = *(const uint4*)(PH + i);
    float4 ci = *(const float4*)(cIn + ((b * 64 + ch) << 10) + d);
    ushort4 o;
    o.x = f2bf(fmaf(ci.x, bf2f((ushort_t)(p.x & 0xFFFF)), bf2f((ushort_t)(p.x >> 16))));
    o.y = f2bf(fmaf(ci.y, bf2f((ushort_t)(p.y & 0xFFFF)), bf2f((ushort_t)(p.y >> 16))));
    o.z = f2bf(fmaf(ci.z, bf2f((ushort_t)(p.z & 0xFFFF)), bf2f((ushort_t)(p.z >> 16))));
    o.w = f2bf(fmaf(ci.w, bf2f((ushort_t)(p.w & 0xFFFF)), bf2f((ushort_t)(p.w >> 16))));
    *(ushort4*)(hout + i) = o;
}

// ---------------------------------------------------------------------------
// Retention with fused W_out GEMM. Each block (nt,h,b) computes its own
// qp tile = (h[n0:n0+64,:].WT_out[h*64:h*64+64,:]^T + bias)*0.125 via a
// 16-iter dbuf DMA GEMM (K/V/S DMAs issued up front, hidden under it),
// then runs chunkwise retention:
// out^T = S^T.q + VT.(masked QK^T), epilogue scale gamma^{nl}.
// LDS 56 KB -> 2 blocks/CU.
// ---------------------------------------------------------------------------
__global__ __launch_bounds__(256)
void retention_fused(const ushort_t* __restrict__ Hb, const ushort_t* __restrict__ WTo,
                     const float* __restrict__ bo, const ushort_t* __restrict__ Kb,
                     const ushort_t* __restrict__ VT, const ushort_t* __restrict__ Sb,
                     const float* __restrict__ gammas, float* __restrict__ Out) {
    __shared__ ushort_t smem[28672];   // 56 KB
    // staging: buf0 A[0,4096) B[4096,8192); buf1 A[8192,12288) B[12288,16384)
    // Ks 16384, Vt 20480, Ss 24576; Qs->0, Ps->4096 after GEMM
    const int tid = threadIdx.x;
    const int nt = blockIdx.x, h = blockIdx.y, b = blockIdx.z;
    const int n0 = nt * 64;
    const float lg = log2f(gammas[h]);
    const int w = tid >> 6, lane = tid & 63, quad = lane >> 4, l15 = lane & 15;
    const int l8 = lane & 7, lr8 = lane >> 3;
    const int nl = w * 16 + l15;
    const size_t bS = (size_t)b * S_;
    const size_t vrow0 = (size_t)((b * H_ + h) * HD_);
    const size_t sbase = ((size_t)((b * H_ + h) * 32 + nt)) * 4096;

    // K/V/S DMAs: complete during the GEMM loop (free latency hiding)
    #pragma unroll
    for (int t = 0; t < 2; ++t) {
        const int row = w * 16 + t * 8 + lr8;
        const int gc = ((l8 ^ (row & 7)) << 3);
        dma16(Kb + (bS + n0 + row) * D_ + h * HD_ + gc, &smem[16384 + row * 64 + l8 * 8]);
        dma16(VT + (vrow0 + row) * S_ + n0 + gc,        &smem[20480 + row * 64 + l8 * 8]);
        dma16(Sb + sbase + (size_t)row * 64 + gc,       &smem[24576 + row * 64 + l8 * 8]);
    }

    auto stage = [&](int k0, int bufo) {
        #pragma unroll
        for (int t = 0; t < 2; ++t) {
            const int row = w * 8 + t * 32 + lr8;
            const int gc = ((l8 ^ (row & 7)) << 3);
            dma16(Hb + (bS + n0 + row) * D_ + k0 + gc, &smem[bufo + row * 64 + l8 * 8]);
            dma16(WTo + ((size_t)(h * 64 + row)) * D_ + k0 + gc,
                  &smem[bufo + 4096 + row * 64 + l8 * 8]);
        }
    };
    stage(0, 0);
    __syncthreads();

    f32x4 acc[4] = {};
    for (int t = 0; t < 16; ++t) {
        const int bufo = (t & 1) * 8192;
        if (t < 15) stage((t + 1) * 64, 8192 - bufo);
        const ushort_t* As = smem + bufo;
        const ushort_t* Bs = smem + bufo + 4096;
        #pragma unroll
        for (int kk = 0; kk < 2; ++kk) {
            bf16x8 af = fragr(As, w * 16 + l15, kk * 4 + quad);
            #pragma unroll
            for (int ct = 0; ct < 4; ++ct) {
                bf16x8 bf = fragr(Bs, ct * 16 + l15, kk * 4 + quad);
                acc[ct] = __builtin_amdgcn_mfma_f32_16x16x32_bf16(af, bf, acc[ct], 0, 0, 0);
            }
        }
        __syncthreads();
    }

    // qp tile -> Qs (swizzled bf16) in dead staging region [0,4096)
    ushort_t* Qs = smem;
    ushort_t* Ps = smem + 4096;
    #pragma unroll
    for (int ct = 0; ct < 4; ++ct) {
        const int n = ct * 16 + l15;
        const float bb = bo[h * 64 + n];
        #pragma unroll
        for (int r = 0; r < 4; ++r) {
            const int m = w * 16 + quad * 4 + r;
            Qs[m * 64 + (((n >> 3) ^ (m & 7)) << 3) + (n & 7)] =
                f2bf((acc[ct][r] + bb) * 0.125f);
        }
    }
    __syncthreads();

    bf16x8 qf0 = fragr(Qs, nl, quad);
    bf16x8 qf1 = fragr(Qs, nl, 4 + quad);
    const ushort_t* Ks = smem + 16384;
    const ushort_t* Vt = smem + 20480;
    const ushort_t* Ss = smem + 24576;

    f32x4 o[4] = {};
    // cross-chunk: o += S^T-rows x Q
    #pragma unroll
    for (int ct = 0; ct < 4; ++ct) {
        bf16x8 sf0 = fragr(Ss, ct * 16 + l15, quad);
        bf16x8 sf1 = fragr(Ss, ct * 16 + l15, 4 + quad);
        o[ct] = __builtin_amdgcn_mfma_f32_16x16x32_bf16(sf0, qf0, o[ct], 0, 0, 0);
        o[ct] = __builtin_amdgcn_mfma_f32_16x16x32_bf16(sf1, qf1, o[ct], 0, 0, 0);
    }
    // intra-chunk scores^T, causal mask, pack -> Ps
    #pragma unroll
    for (int mt2 = 0; mt2 < 4; ++mt2) {
        bf16x8 kf0 = fragr(Ks, mt2 * 16 + l15, quad);
        bf16x8 kf1 = fragr(Ks, mt2 * 16 + l15, 4 + quad);
        f32x4 s = {};
        s = __builtin_amdgcn_mfma_f32_16x16x32_bf16(kf0, qf0, s, 0, 0, 0);
        s = __builtin_amdgcn_mfma_f32_16x16x32_bf16(kf1, qf1, s, 0, 0, 0);
        const int mbase = mt2 * 16 + quad * 4;
        #pragma unroll
        for (int r = 0; r < 4; ++r)
            if (nl < mbase + r) s[r] = 0.0f;
        uint2 pw; pw.x = pkt(s[0], s[1]); pw.y = pkt(s[2], s[3]);
        const int chunk = mbase >> 3;
        *(uint2*)&Ps[nl * 64 + ((chunk ^ (nl & 7)) << 3) + (mbase & 7)] = pw;
    }
    // PV: o += Vt-rows x Ps-row-nl  (Ps rows wave-private)
    bf16x8 pf0 = fragr(Ps, nl, quad);
    bf16x8 pf1 = fragr(Ps, nl, 4 + quad);
    #pragma unroll
    for (int ct = 0; ct < 4; ++ct) {
        bf16x8 vf0 = fragr(Vt, ct * 16 + l15, quad);
        bf16x8 vf1 = fragr(Vt, ct * 16 + l15, 4 + quad);
        o[ct] = __builtin_amdgcn_mfma_f32_16x16x32_bf16(vf0, pf0, o[ct], 0, 0, 0);
        o[ct] = __builtin_amdgcn_mfma_f32_16x16x32_bf16(vf1, pf1, o[ct], 0, 0, 0);
    }

    const float esc = exp2f((float)nl * lg);
    const size_t ob = (bS + n0 + nl) * D_ + h * HD_;
    #pragma unroll
    for (int ct = 0; ct < 4; ++ct) {
        f32x4 t = o[ct] * esc;
        *(f32x4*)(Out + ob + ct * 16 + quad * 4) = t;
    }
}

// ---------------------------------------------------------------------------
extern "C" void kernel_launch(void* const* d_in, const int* in_sizes, int n_in,
                              void* d_out, int out_size, void* d_ws, size_t ws_size,
                              hipStream_t stream) {
    const float* q      = (const float*)d_in[0];
    const float* k      = (const float*)d_in[1];
    const float* v      = (const float*)d_in[2];
    const float* W_in   = (const float*)d_in[3];
    const float* b_in   = (const float*)d_in[4];
    const float* W_gate = (const float*)d_in[5];
    const float* b_gate = (const float*)d_in[6];
    const float* W_out  = (const float*)d_in[7];
    const float* b_out  = (const float*)d_in[8];
    const float* gammas = (const float*)d_in[9];
    float* out = (float*)d_out;

    char* ws = (char*)d_ws;
    const size_t MB = 1024 * 1024;
    ushort_t* q_bf    = (ushort_t*)(ws);              // [0,8)
    ushort_t* k_bf    = (ushort_t*)(ws + 8 * MB);     // [8,16)
    ushort_t* VT      = (ushort_t*)(ws + 16 * MB);    // [16,24)
    ushort_t* WT_in   = (ushort_t*)(ws + 24 * MB);    // [24,26)
    ushort_t* WT_gate = (ushort_t*)(ws + 26 * MB);    // [26,28)
    ushort_t* WT_out  = (ushort_t*)(ws + 28 * MB);    // [28,30)
    ushort_t* Sb      = (ushort_t*)(ws + 30 * MB);    // [30,38)
    ushort_t* Gg      = (ushort_t*)(ws + 38 * MB);    // [38,46) dead after state_scan
    uint_t*   PH      = (uint_t*)(ws + 48 * MB);      // [48,64)
    ushort_t* h_bf    = (ushort_t*)(ws + 64 * MB);    // [64,72)
    float*    cA      = (float*)(ws + 72 * MB);
    float*    cU      = (float*)(ws + 72 * MB + 512 * 1024);
    float*    cIn     = (float*)(ws + 73 * MB);

    prep<<<8192, 256, 0, stream>>>(W_in, W_gate, W_out, WT_in, WT_gate, WT_out,
                                   q, q_bf, k, v, gammas, k_bf, VT, Gg);

    state_scan<<<dim3(4, H_, B_), 256, 0, stream>>>(Gg, gammas, Sb);

    gemm_dual_scan<<<dim3(D_ / 64, M_ / 128), 256, 0, stream>>>(
        q_bf, WT_in, WT_gate, b_in, b_gate, PH, cA, cU);

    scan_pass2<<<32, 64, 0, stream>>>(cA, cU, cIn);
    scan_fix<<<(M_ * D_) / 1024, 256, 0, stream>>>(PH, cIn, h_bf);

    retention_fused<<<dim3(S_ / 64, H_, B_), 256, 0, stream>>>(
        h_bf, WT_out, b_out, k_bf, VT, Sb, gammas, out);
}